// Round 11
// baseline (711.910 us; speedup 1.0000x reference)
//
#include <hip/hip_runtime.h>
#include <hip/hip_bf16.h>

#define NN 8192
#define DD 512

typedef unsigned short u16;
typedef __bf16 bf16_t;
typedef bf16_t bf16x8 __attribute__((ext_vector_type(8)));
typedef float f32x4 __attribute__((ext_vector_type(4)));

__device__ __forceinline__ float bf2f(u16 h) {
    union { unsigned u; float f; } v; v.u = ((unsigned)h) << 16; return v.f;
}
__device__ __forceinline__ float bflo(unsigned u) {
    union { unsigned u; float f; } v; v.u = u << 16; return v.f;
}
__device__ __forceinline__ float bfhi(unsigned u) {
    union { unsigned u; float f; } v; v.u = u & 0xFFFF0000u; return v.f;
}
__device__ __forceinline__ u16 f2bf(float f) {
    union { float f; unsigned u; } v; v.f = f;
    unsigned r = v.u + 0x7fffu + ((v.u >> 16) & 1u);
    return (u16)(r >> 16);
}

// Fused fp32->bf16 convert of the 7 GEMM operands, 8 elems/thread.
__global__ __launch_bounds__(256) void cvt7(
        const float* __restrict__ s0, u16* __restrict__ d0,
        const float* __restrict__ s1, u16* __restrict__ d1,
        const float* __restrict__ s2, u16* __restrict__ d2,
        const float* __restrict__ s3, u16* __restrict__ d3,
        const float* __restrict__ s4, u16* __restrict__ d4,
        const float* __restrict__ s5, u16* __restrict__ d5,
        const float* __restrict__ s6, u16* __restrict__ d6) {
    size_t v = ((size_t)blockIdx.x * 256 + threadIdx.x) * 8;
    const float* s; u16* d; size_t off;
    if (v < 4194304)      { s = s0; d = d0; off = v; }
    else if (v < 8388608) { s = s1; d = d1; off = v - 4194304; }
    else if (v < 8650752) { s = s2; d = d2; off = v - 8388608; }
    else if (v < 8912896) { s = s3; d = d3; off = v - 8650752; }
    else if (v < 9699328) { s = s4; d = d4; off = v - 8912896; }
    else if (v < 9961472) { s = s5; d = d5; off = v - 9699328; }
    else                  { s = s6; d = d6; off = v - 9961472; }
    float4 a = *(const float4*)(s + off);
    float4 b = *(const float4*)(s + off + 4);
    ushort4 o0 = make_ushort4(f2bf(a.x), f2bf(a.y), f2bf(a.z), f2bf(a.w));
    ushort4 o1 = make_ushort4(f2bf(b.x), f2bf(b.y), f2bf(b.z), f2bf(b.w));
    *(ushort4*)(d + off) = o0;
    *(ushort4*)(d + off + 4) = o1;
}

// C[M][Nc] = act(A[M][K] @ B[Nc][K]^T + bias), bf16 in/out, fp32 accum/bias.
// m97-class async staging (global_load_lds width=16), 128x128 tile, BK=64,
// 256 thr = 4 waves (2x2), wave tile 64x64 = 4x4 MFMA 16x16x32.
// Epilogue: LDS-swizzle (fragment order -> row-major) then 16B coalesced stores.
// SPLIT: blocks with blockIdx.y >= halfY use B2/bias2 (fused two-weight GEMM).
#define EPS_LDS 136  // epilogue LDS row stride in u16 (16B-aligned rows, 4-way max)
template<bool RELU, bool BIAS, bool SPLIT>
__global__ __launch_bounds__(256) void gemm_bt(const u16* __restrict__ A,
        const u16* __restrict__ B, const float* __restrict__ bias,
        const u16* __restrict__ B2, const float* __restrict__ bias2, int halfY,
        u16* __restrict__ C, int M, int Nc, int K) {
    __shared__ alignas(16) u16 Smem[128 * EPS_LDS];  // 34 KB; staging uses first 32 KB
    u16* As = Smem;
    u16* Bs = Smem + 128 * 64;
    const int t = threadIdx.x;
    const int lane = t & 63;
    const int wave = t >> 6;
    const int wm = (wave >> 1) * 64;
    const int wn = (wave & 1) * 64;
    const int rowA = blockIdx.y * 128;
    const int rowB = blockIdx.x * 128;
    if (SPLIT && (int)blockIdx.y >= halfY) { B = B2; bias = bias2; }

    f32x4 acc[4][4] = {};

    const int mrow = lane & 15;
    const int kk = (lane >> 4) * 8;

    for (int k0 = 0; k0 < K; k0 += 64) {
        __syncthreads();  // prev iteration's LDS readers done
        #pragma unroll
        for (int r = 0; r < 4; ++r) {
            int chunk = r * 256 + t;              // row = chunk>>3, col8 = (chunk&7)*8
            const u16* srcA = A + (size_t)(rowA + (chunk >> 3)) * K + k0 + (chunk & 7) * 8;
            __builtin_amdgcn_global_load_lds(
                (const __attribute__((address_space(1))) void*)srcA,
                (__attribute__((address_space(3))) void*)(As + chunk * 8), 16, 0, 0);
            const u16* srcB = B + (size_t)(rowB + (chunk >> 3)) * K + k0 + (chunk & 7) * 8;
            __builtin_amdgcn_global_load_lds(
                (const __attribute__((address_space(1))) void*)srcB,
                (__attribute__((address_space(3))) void*)(Bs + chunk * 8), 16, 0, 0);
        }
        __syncthreads();  // drains vmcnt -> LDS valid
        #pragma unroll
        for (int ks = 0; ks < 64; ks += 32) {
            bf16x8 af[4], bfv[4];
            #pragma unroll
            for (int i = 0; i < 4; ++i)
                af[i] = *(const bf16x8*)(As + (wm + i * 16 + mrow) * 64 + ks + kk);
            #pragma unroll
            for (int j = 0; j < 4; ++j)
                bfv[j] = *(const bf16x8*)(Bs + (wn + j * 16 + mrow) * 64 + ks + kk);
            #pragma unroll
            for (int i = 0; i < 4; ++i)
                #pragma unroll
                for (int j = 0; j < 4; ++j)
                    acc[i][j] = __builtin_amdgcn_mfma_f32_16x16x32_bf16(af[i], bfv[j], acc[i][j], 0, 0, 0);
        }
    }

    // epilogue: C/D layout (m89/m91): col = lane&15, row = (lane>>4)*4 + reg.
    __syncthreads();  // staging reads done -> reuse Smem for the C tile
    const int er0 = wm + (lane >> 4) * 4;
    const int ec0 = wn + (lane & 15);
    #pragma unroll
    for (int j = 0; j < 4; ++j) {
        int c = ec0 + j * 16;
        float bv = BIAS ? bias[rowB + c] : 0.0f;
        #pragma unroll
        for (int i = 0; i < 4; ++i) {
            #pragma unroll
            for (int r = 0; r < 4; ++r) {
                float v = acc[i][j][r] + bv;
                if (RELU) v = fmaxf(v, 0.0f);
                Smem[(er0 + i * 16 + r) * EPS_LDS + c] = f2bf(v);
            }
        }
    }
    __syncthreads();
    // coalesced store: 2048 chunks of 8 u16; wave covers 4 rows x 256 B contiguous
    #pragma unroll
    for (int pass = 0; pass < 8; ++pass) {
        int chunk = pass * 256 + t;
        int rloc = chunk >> 4, coff = (chunk & 15) * 8;
        bf16x8 v = *(const bf16x8*)(Smem + rloc * EPS_LDS + coff);
        *(bf16x8*)(C + (size_t)(rowA + rloc) * Nc + rowB + coff) = v;
    }
}

// Fused LayerNorm over D=512 for BOTH modalities; y = [y0;y1] (16384 rows).
__global__ __launch_bounds__(256) void ln2_kernel(const u16* __restrict__ y,
        const float* __restrict__ g0, const float* __restrict__ b0,
        const float* __restrict__ g1, const float* __restrict__ b1,
        u16* __restrict__ seq) {
    __shared__ float sred[4];
    int n = blockIdx.x, t = threadIdx.x;
    int modality = n >> 13, node = n & (NN - 1);
    const float* g = modality ? g1 : g0;
    const float* b = modality ? b1 : b0;
    const u16* yr = y + (size_t)n * DD;
    float x0 = bf2f(yr[t]), x1 = bf2f(yr[t + 256]);
    float s = x0 + x1;
    for (int off = 32; off; off >>= 1) s += __shfl_xor(s, off);
    if ((t & 63) == 0) sred[t >> 6] = s;
    __syncthreads();
    float mean = (sred[0] + sred[1] + sred[2] + sred[3]) * (1.0f / DD);
    __syncthreads();
    float d0 = x0 - mean, d1 = x1 - mean;
    float vs = d0 * d0 + d1 * d1;
    for (int off = 32; off; off >>= 1) vs += __shfl_xor(vs, off);
    if ((t & 63) == 0) sred[t >> 6] = vs;
    __syncthreads();
    float var = (sred[0] + sred[1] + sred[2] + sred[3]) * (1.0f / DD);
    float inv = rsqrtf(var + 1e-5f);
    u16* out = seq + (size_t)node * (2 * DD) + modality * DD;
    out[t]       = f2bf(d0 * inv * g[t]       + b[t]);
    out[t + 256] = f2bf(d1 * inv * g[t + 256] + b[t + 256]);
}

// MHA over 2 tokens, 8 heads of 64. One wave per (node, head). ctxm = mean_t(ctx_t).
__global__ __launch_bounds__(256) void attn_kernel(const u16* __restrict__ qkv,
        u16* __restrict__ ctxm) {
    int gid = blockIdx.x * 4 + (threadIdx.x >> 6);
    int lane = threadIdx.x & 63;
    int n = gid >> 3, h = gid & 7;
    const u16* r0 = qkv + (size_t)(n * 2) * 1536;
    const u16* r1 = r0 + 1536;
    float q0 = bf2f(r0[h * 64 + lane]);
    float k0 = bf2f(r0[512 + h * 64 + lane]);
    float v0 = bf2f(r0[1024 + h * 64 + lane]);
    float q1 = bf2f(r1[h * 64 + lane]);
    float k1 = bf2f(r1[512 + h * 64 + lane]);
    float v1 = bf2f(r1[1024 + h * 64 + lane]);
    float p00 = q0 * k0, p01 = q0 * k1, p10 = q1 * k0, p11 = q1 * k1;
    for (int off = 32; off; off >>= 1) {
        p00 += __shfl_xor(p00, off);
        p01 += __shfl_xor(p01, off);
        p10 += __shfl_xor(p10, off);
        p11 += __shfl_xor(p11, off);
    }
    const float sc = 0.125f;  // 1/sqrt(64)
    float s00 = p00 * sc, s01 = p01 * sc, s10 = p10 * sc, s11 = p11 * sc;
    float m0 = fmaxf(s00, s01), e00 = __expf(s00 - m0), e01 = __expf(s01 - m0);
    float a00 = e00 / (e00 + e01), a01 = e01 / (e00 + e01);
    float m1 = fmaxf(s10, s11), e10 = __expf(s10 - m1), e11 = __expf(s11 - m1);
    float a10 = e10 / (e10 + e11), a11 = e11 / (e10 + e11);
    float c0 = a00 * v0 + a01 * v1;
    float c1 = a10 * v0 + a11 * v1;
    ctxm[(size_t)n * 512 + h * 64 + lane] = f2bf(0.5f * (c0 + c1));
}

// Top-16 + softmax stats over bf16 S. ONE WAVE PER ROW, streaming.
__global__ __launch_bounds__(256) void topk_bf16(const u16* __restrict__ S,
        float* __restrict__ topv, int* __restrict__ topi) {
    const float NEG = -3e38f;
    int row = blockIdx.x * 4 + (threadIdx.x >> 6);
    int lane = threadIdx.x & 63;
    const u16* Sr = S + (size_t)row * NN;

    float m = NEG, l = 0.0f;
    float t1v = NEG, t2v = NEG;
    int t1i = 0x7FFFFFFF, t2i = 0x7FFFFFFF;

    #pragma unroll
    for (int p = 0; p < 16; ++p) {
        uint4 raw = *(const uint4*)(Sr + p * 512 + lane * 8);
        int base = p * 512 + lane * 8;
        #pragma unroll
        for (int q = 0; q < 4; ++q) {
            unsigned w = (&raw.x)[q];
            #pragma unroll
            for (int h = 0; h < 2; ++h) {
                float x = h ? bfhi(w) : bflo(w);
                int xi = base + q * 2 + h;
                if (x > m) { l = l * __expf(m - x) + 1.0f; m = x; }
                else l += __expf(x - m);
                bool g1 = x > t1v, g2 = x > t2v;
                t2v = g1 ? t1v : (g2 ? x : t2v);
                t2i = g1 ? t1i : (g2 ? xi : t2i);
                t1v = g1 ? x : t1v;
                t1i = g1 ? xi : t1i;
            }
        }
    }
    #pragma unroll
    for (int off = 32; off; off >>= 1) {
        float om = __shfl_xor(m, off);
        float ol = __shfl_xor(l, off);
        float nm = fmaxf(m, om);
        l = l * __expf(m - nm) + ol * __expf(om - nm);
        m = nm;
    }

    unsigned mk0 = 0, mk1 = 0, mk2 = 0, mk3 = 0;
    float cv = t1v; int ci = t1i;
    float bv = t2v; int bi = t2i;
    for (int r = 0; r < 16; ++r) {
        float wv = cv; int wi = ci;
        #pragma unroll
        for (int off = 32; off; off >>= 1) {
            float ov = __shfl_xor(wv, off);
            int oi = __shfl_xor(wi, off);
            if (ov > wv || (ov == wv && oi < wi)) { wv = ov; wi = oi; }
        }
        if (lane == 0) {
            topv[(size_t)row * 16 + r] = __expf(wv - m) / l;
            topi[(size_t)row * 16 + r] = wi;
        }
        if (wi == ci) {
            int slot = ((wi >> 9) << 3) | (wi & 7);
            unsigned bit = 1u << (slot & 31);
            if (slot < 32) mk0 |= bit; else if (slot < 64) mk1 |= bit;
            else if (slot < 96) mk2 |= bit; else mk3 |= bit;
            cv = bv; ci = bi;
            bv = NEG; bi = 0x7FFFFFFF;
            if (ci == 0x7FFFFFFF) {
                float nb = NEG; int ni = 0x7FFFFFFF;
                #pragma unroll
                for (int p = 0; p < 16; ++p) {
                    uint4 raw = *(const uint4*)(Sr + p * 512 + lane * 8);
                    int base = p * 512 + lane * 8;
                    #pragma unroll
                    for (int q = 0; q < 4; ++q) {
                        unsigned w = (&raw.x)[q];
                        #pragma unroll
                        for (int h = 0; h < 2; ++h) {
                            int sl = p * 8 + q * 2 + h;
                            unsigned mw = (sl < 32) ? mk0 : (sl < 64) ? mk1
                                        : (sl < 96) ? mk2 : mk3;
                            float x = ((mw >> (sl & 31)) & 1u) ? NEG
                                    : (h ? bfhi(w) : bflo(w));
                            if (x > nb) { nb = x; ni = base + q * 2 + h; }
                        }
                    }
                }
                cv = nb; ci = ni;
            }
        }
    }
}

// Fused scatter + diag (exact ref semantics, race-free).
__global__ __launch_bounds__(256) void scatter_diag(const float* __restrict__ topv,
        const int* __restrict__ topi, float* __restrict__ H) {
    int tk = blockIdx.x * 256 + threadIdx.x;  // 544 * 256 = 139264
    if (tk < NN * 16) {
        int i = tk >> 4;
        int idx = topi[tk];
        H[(size_t)idx * NN + i] = topv[tk];
    } else {
        int c = tk - NN * 16;
        const int* ti = topi + c * 16;
        bool self = false;
        #pragma unroll
        for (int j = 0; j < 16; ++j) self |= (ti[j] == c);
        if (!self) H[(size_t)c * NN + c] = 1.0f;
    }
}

// ew = max(sigmoid(hidden @ w2 + b2), 1e-8), fp32 out. One wave per node.
__global__ __launch_bounds__(256) void ew_kernel(const u16* __restrict__ hidden,
        const float* __restrict__ w2, const float* __restrict__ b2, float* __restrict__ out) {
    int n = blockIdx.x * 4 + (threadIdx.x >> 6);
    int lane = threadIdx.x & 63;
    const u16* hr = hidden + (size_t)n * 256;
    float s = 0.0f;
    #pragma unroll
    for (int p = 0; p < 4; ++p) s += bf2f(hr[lane + p * 64]) * w2[lane + p * 64];
    for (int off = 32; off; off >>= 1) s += __shfl_xor(s, off);
    if (lane == 0) {
        float z = s + b2[0];
        float sig = 1.0f / (1.0f + __expf(-z));
        out[n] = fmaxf(sig, 1e-8f);
    }
}

extern "C" void kernel_launch(void* const* d_in, const int* in_sizes, int n_in,
                              void* d_out, int out_size, void* d_ws, size_t ws_size,
                              hipStream_t stream) {
    const float* x0    = (const float*)d_in[0];
    const float* x1    = (const float*)d_in[1];
    const float* w_p0  = (const float*)d_in[2];
    const float* b_p0  = (const float*)d_in[3];
    const float* g0    = (const float*)d_in[4];
    const float* beta0 = (const float*)d_in[5];
    const float* w_p1  = (const float*)d_in[6];
    const float* b_p1  = (const float*)d_in[7];
    const float* g1    = (const float*)d_in[8];
    const float* beta1 = (const float*)d_in[9];
    const float* in_w  = (const float*)d_in[10];
    const float* in_b  = (const float*)d_in[11];
    const float* out_w = (const float*)d_in[12];
    const float* out_b = (const float*)d_in[13];
    const float* ew_w1 = (const float*)d_in[14];
    const float* ew_b1 = (const float*)d_in[15];
    const float* ew_w2 = (const float*)d_in[16];
    const float* ew_b2 = (const float*)d_in[17];

    float* Hf = (float*)d_out;                  // [8192][8192] fp32 (256 MB)
    float* ew_out = Hf + (size_t)NN * NN;       // [8192] fp32

    // bf16 staging inside the fp32 H region (dead before memset rewrites H).
    u16* Hu = (u16*)d_out;
    u16* x0b    = Hu;                           //   0.. 8 MB  (x0b||x1b contiguous)
    u16* x1b    = Hu + 4194304;                 //   8..16 MB
    u16* y01    = Hu + 8388608;                 //  16..32 MB  [16384][512]
    u16* seq    = Hu + 16777216;                //  32..48 MB  [8192][2][512]
    u16* qkv    = Hu + 25165824;                //  48..96 MB  [16384][1536]
    u16* ctxm   = Hu + 50331648;                //  96..104 MB
    u16* hidden = Hu + 54525952;                // 104..108 MB [8192][256]
    u16* wp0b   = Hu + 60817408;                // 116 MB.. weights (3.25 MB)
    u16* wp1b   = wp0b + 262144;
    u16* inwb   = wp1b + 262144;                // [1536][512]
    u16* outwb  = inwb + 786432;
    u16* eww1b  = outwb + 262144;               // [256][512]
    u16* Sb     = Hu + 67108864;                // 128..256 MB raw scores bf16
    // ws: survives the S GEMM (9 MB)
    char* ws = (char*)d_ws;
    u16* fusedB = (u16*)ws;                     // [8192][512] bf16
    float* topv = (float*)(ws + (8u << 20));
    int*   topi = (int*)(ws + (8u << 20) + 524288);

    dim3 blk(256);
    const int BIG = 1 << 30;
    // 0: fp32 -> bf16 for all MFMA operands
    cvt7<<<dim3(4928), blk, 0, stream>>>(x0, x0b, x1, x1b, w_p0, wp0b, w_p1, wp1b,
                                         in_w, inwb, out_w, outwb, ew_w1, eww1b);
    // 1: both modality projections in one launch
    gemm_bt<true, true, true><<<dim3(4, 128), blk, 0, stream>>>(
        x0b, wp0b, b_p0, wp1b, b_p1, 64, y01, 2 * NN, DD, DD);
    // 2: fused LayerNorm -> seq
    ln2_kernel<<<dim3(2 * NN), blk, 0, stream>>>(y01, g0, beta0, g1, beta1, seq);
    // 3: qkv = seq @ in_w^T + in_b
    gemm_bt<false, true, false><<<dim3(12, 128), blk, 0, stream>>>(
        seq, inwb, in_b, nullptr, nullptr, BIG, qkv, 2 * NN, 1536, DD);
    // 4: attention -> ctxm
    attn_kernel<<<dim3(NN * 8 / 4), blk, 0, stream>>>(qkv, ctxm);
    // 5: fused = ctxm @ out_w^T + out_b
    gemm_bt<false, true, false><<<dim3(4, 64), blk, 0, stream>>>(
        ctxm, outwb, out_b, nullptr, nullptr, BIG, fusedB, NN, DD, DD);
    // 6: hidden = relu(fused @ ew_w1^T + ew_b1)
    gemm_bt<true, true, false><<<dim3(2, 64), blk, 0, stream>>>(
        fusedB, eww1b, ew_b1, nullptr, nullptr, BIG, hidden, NN, 256, DD);
    // 7: ew
    ew_kernel<<<dim3(NN / 4), blk, 0, stream>>>(hidden, ew_w2, ew_b2, ew_out);
    // 8: S = fused @ fused^T (bf16)
    gemm_bt<false, false, false><<<dim3(64, 64), blk, 0, stream>>>(
        fusedB, fusedB, nullptr, nullptr, nullptr, BIG, Sb, NN, NN, DD);
    // 9: top-16 + softmax stats
    topk_bf16<<<dim3(NN / 4), blk, 0, stream>>>(Sb, topv, topi);
    // 10: H := 0 (fast fill path)
    hipMemsetAsync(Hf, 0, (size_t)NN * NN * sizeof(float), stream);
    // 11: fused scatter + conditional diag
    scatter_diag<<<dim3((NN * 16 + NN) / 256), blk, 0, stream>>>(topv, topi, Hf);
}

// Round 12
// 690.874 us; speedup vs baseline: 1.0304x; 1.0304x over previous
//
#include <hip/hip_runtime.h>
#include <hip/hip_bf16.h>

#define NN 8192
#define DD 512

typedef unsigned short u16;
typedef __bf16 bf16_t;
typedef bf16_t bf16x8 __attribute__((ext_vector_type(8)));
typedef float f32x4 __attribute__((ext_vector_type(4)));

__device__ __forceinline__ float bf2f(u16 h) {
    union { unsigned u; float f; } v; v.u = ((unsigned)h) << 16; return v.f;
}
__device__ __forceinline__ float bflo(unsigned u) {
    union { unsigned u; float f; } v; v.u = u << 16; return v.f;
}
__device__ __forceinline__ float bfhi(unsigned u) {
    union { unsigned u; float f; } v; v.u = u & 0xFFFF0000u; return v.f;
}
__device__ __forceinline__ u16 f2bf(float f) {
    union { float f; unsigned u; } v; v.f = f;
    unsigned r = v.u + 0x7fffu + ((v.u >> 16) & 1u);
    return (u16)(r >> 16);
}

// Fused fp32->bf16 convert of the 7 GEMM operands, 8 elems/thread.
__global__ __launch_bounds__(256) void cvt7(
        const float* __restrict__ s0, u16* __restrict__ d0,
        const float* __restrict__ s1, u16* __restrict__ d1,
        const float* __restrict__ s2, u16* __restrict__ d2,
        const float* __restrict__ s3, u16* __restrict__ d3,
        const float* __restrict__ s4, u16* __restrict__ d4,
        const float* __restrict__ s5, u16* __restrict__ d5,
        const float* __restrict__ s6, u16* __restrict__ d6) {
    size_t v = ((size_t)blockIdx.x * 256 + threadIdx.x) * 8;
    const float* s; u16* d; size_t off;
    if (v < 4194304)      { s = s0; d = d0; off = v; }
    else if (v < 8388608) { s = s1; d = d1; off = v - 4194304; }
    else if (v < 8650752) { s = s2; d = d2; off = v - 8388608; }
    else if (v < 8912896) { s = s3; d = d3; off = v - 8650752; }
    else if (v < 9699328) { s = s4; d = d4; off = v - 8912896; }
    else if (v < 9961472) { s = s5; d = d5; off = v - 9699328; }
    else                  { s = s6; d = d6; off = v - 9961472; }
    float4 a = *(const float4*)(s + off);
    float4 b = *(const float4*)(s + off + 4);
    ushort4 o0 = make_ushort4(f2bf(a.x), f2bf(a.y), f2bf(a.z), f2bf(a.w));
    ushort4 o1 = make_ushort4(f2bf(b.x), f2bf(b.y), f2bf(b.z), f2bf(b.w));
    *(ushort4*)(d + off) = o0;
    *(ushort4*)(d + off + 4) = o1;
}

// C[M][Nc] = act(A[M][K] @ B[Nc][K]^T + bias), bf16 in/out, fp32 accum/bias.
// m97-class async staging, 128x128 tile, BK=64, 4 waves (2x2), 4x4 MFMA 16x16x32.
// LDS-swizzled coalesced epilogue. SPLIT: blocks y >= halfY use B2/bias2.
#define EPS_LDS 136
template<bool RELU, bool BIAS, bool SPLIT>
__global__ __launch_bounds__(256) void gemm_bt(const u16* __restrict__ A,
        const u16* __restrict__ B, const float* __restrict__ bias,
        const u16* __restrict__ B2, const float* __restrict__ bias2, int halfY,
        u16* __restrict__ C, int M, int Nc, int K) {
    __shared__ alignas(16) u16 Smem[128 * EPS_LDS];
    u16* As = Smem;
    u16* Bs = Smem + 128 * 64;
    const int t = threadIdx.x;
    const int lane = t & 63;
    const int wave = t >> 6;
    const int wm = (wave >> 1) * 64;
    const int wn = (wave & 1) * 64;
    const int rowA = blockIdx.y * 128;
    const int rowB = blockIdx.x * 128;
    if (SPLIT && (int)blockIdx.y >= halfY) { B = B2; bias = bias2; }

    f32x4 acc[4][4] = {};
    const int mrow = lane & 15;
    const int kk = (lane >> 4) * 8;

    for (int k0 = 0; k0 < K; k0 += 64) {
        __syncthreads();
        #pragma unroll
        for (int r = 0; r < 4; ++r) {
            int chunk = r * 256 + t;
            const u16* srcA = A + (size_t)(rowA + (chunk >> 3)) * K + k0 + (chunk & 7) * 8;
            __builtin_amdgcn_global_load_lds(
                (const __attribute__((address_space(1))) void*)srcA,
                (__attribute__((address_space(3))) void*)(As + chunk * 8), 16, 0, 0);
            const u16* srcB = B + (size_t)(rowB + (chunk >> 3)) * K + k0 + (chunk & 7) * 8;
            __builtin_amdgcn_global_load_lds(
                (const __attribute__((address_space(1))) void*)srcB,
                (__attribute__((address_space(3))) void*)(Bs + chunk * 8), 16, 0, 0);
        }
        __syncthreads();
        #pragma unroll
        for (int ks = 0; ks < 64; ks += 32) {
            bf16x8 af[4], bfv[4];
            #pragma unroll
            for (int i = 0; i < 4; ++i)
                af[i] = *(const bf16x8*)(As + (wm + i * 16 + mrow) * 64 + ks + kk);
            #pragma unroll
            for (int j = 0; j < 4; ++j)
                bfv[j] = *(const bf16x8*)(Bs + (wn + j * 16 + mrow) * 64 + ks + kk);
            #pragma unroll
            for (int i = 0; i < 4; ++i)
                #pragma unroll
                for (int j = 0; j < 4; ++j)
                    acc[i][j] = __builtin_amdgcn_mfma_f32_16x16x32_bf16(af[i], bfv[j], acc[i][j], 0, 0, 0);
        }
    }

    __syncthreads();
    const int er0 = wm + (lane >> 4) * 4;
    const int ec0 = wn + (lane & 15);
    #pragma unroll
    for (int j = 0; j < 4; ++j) {
        int c = ec0 + j * 16;
        float bv = BIAS ? bias[rowB + c] : 0.0f;
        #pragma unroll
        for (int i = 0; i < 4; ++i) {
            #pragma unroll
            for (int r = 0; r < 4; ++r) {
                float v = acc[i][j][r] + bv;
                if (RELU) v = fmaxf(v, 0.0f);
                Smem[(er0 + i * 16 + r) * EPS_LDS + c] = f2bf(v);
            }
        }
    }
    __syncthreads();
    #pragma unroll
    for (int pass = 0; pass < 8; ++pass) {
        int chunk = pass * 256 + t;
        int rloc = chunk >> 4, coff = (chunk & 15) * 8;
        bf16x8 v = *(const bf16x8*)(Smem + rloc * EPS_LDS + coff);
        *(bf16x8*)(C + (size_t)(rowA + rloc) * Nc + rowB + coff) = v;
    }
}

// Symmetric S = F @ F^T (bf16 out, no bias/relu). Upper-triangle blocks only
// (bx >= by); off-diagonal blocks store the tile twice (normal + transposed).
// Epilogue LDS stride 129: transposed gather lane-stride 516 dw == 4 mod 32
// -> 8 banks / 16 lanes -> 2-way (free, m136).
#define SYM_LDS 129
__global__ __launch_bounds__(256) void gemm_sym(const u16* __restrict__ F,
        u16* __restrict__ C) {
    __shared__ alignas(16) u16 Smem[128 * SYM_LDS];  // 33 KB; staging uses first 32 KB
    const int bx = blockIdx.x, by = blockIdx.y;
    if (bx < by) return;  // uniform early-exit before any barrier
    u16* As = Smem;
    u16* Bs = Smem + 128 * 64;
    const int t = threadIdx.x;
    const int lane = t & 63;
    const int wave = t >> 6;
    const int wm = (wave >> 1) * 64;
    const int wn = (wave & 1) * 64;
    const int rowI = by * 128;   // S rows
    const int rowJ = bx * 128;   // S cols

    f32x4 acc[4][4] = {};
    const int mrow = lane & 15;
    const int kk = (lane >> 4) * 8;

    for (int k0 = 0; k0 < DD; k0 += 64) {
        __syncthreads();
        #pragma unroll
        for (int r = 0; r < 4; ++r) {
            int chunk = r * 256 + t;
            const u16* srcA = F + (size_t)(rowI + (chunk >> 3)) * DD + k0 + (chunk & 7) * 8;
            __builtin_amdgcn_global_load_lds(
                (const __attribute__((address_space(1))) void*)srcA,
                (__attribute__((address_space(3))) void*)(As + chunk * 8), 16, 0, 0);
            const u16* srcB = F + (size_t)(rowJ + (chunk >> 3)) * DD + k0 + (chunk & 7) * 8;
            __builtin_amdgcn_global_load_lds(
                (const __attribute__((address_space(1))) void*)srcB,
                (__attribute__((address_space(3))) void*)(Bs + chunk * 8), 16, 0, 0);
        }
        __syncthreads();
        #pragma unroll
        for (int ks = 0; ks < 64; ks += 32) {
            bf16x8 af[4], bfv[4];
            #pragma unroll
            for (int i = 0; i < 4; ++i)
                af[i] = *(const bf16x8*)(As + (wm + i * 16 + mrow) * 64 + ks + kk);
            #pragma unroll
            for (int j = 0; j < 4; ++j)
                bfv[j] = *(const bf16x8*)(Bs + (wn + j * 16 + mrow) * 64 + ks + kk);
            #pragma unroll
            for (int i = 0; i < 4; ++i)
                #pragma unroll
                for (int j = 0; j < 4; ++j)
                    acc[i][j] = __builtin_amdgcn_mfma_f32_16x16x32_bf16(af[i], bfv[j], acc[i][j], 0, 0, 0);
        }
    }

    __syncthreads();
    const int er0 = wm + (lane >> 4) * 4;
    const int ec0 = wn + (lane & 15);
    #pragma unroll
    for (int j = 0; j < 4; ++j) {
        int c = ec0 + j * 16;
        #pragma unroll
        for (int i = 0; i < 4; ++i) {
            #pragma unroll
            for (int r = 0; r < 4; ++r)
                Smem[(er0 + i * 16 + r) * SYM_LDS + c] = f2bf(acc[i][j][r]);
        }
    }
    __syncthreads();
    // normal store: S[rowI + r][rowJ + c]
    #pragma unroll
    for (int pass = 0; pass < 8; ++pass) {
        int chunk = pass * 256 + t;
        int rloc = chunk >> 4, coff = (chunk & 15) * 8;
        union { u16 us[8]; bf16x8 v; } buf;
        #pragma unroll
        for (int k = 0; k < 8; ++k) buf.us[k] = Smem[rloc * SYM_LDS + coff + k];
        *(bf16x8*)(C + (size_t)(rowI + rloc) * NN + rowJ + coff) = buf.v;
    }
    if (bx != by) {
        // transposed store: S[rowJ + tr][rowI + roff..+8] = tile[roff+k][tr]
        #pragma unroll
        for (int pass = 0; pass < 8; ++pass) {
            int chunk = pass * 256 + t;
            int tr = chunk >> 4, roff = (chunk & 15) * 8;
            union { u16 us[8]; bf16x8 v; } buf;
            #pragma unroll
            for (int k = 0; k < 8; ++k) buf.us[k] = Smem[(roff + k) * SYM_LDS + tr];
            *(bf16x8*)(C + (size_t)(rowJ + tr) * NN + rowI + roff) = buf.v;
        }
    }
}

// Fused LayerNorm over D=512 for BOTH modalities; y = [y0;y1] (16384 rows).
__global__ __launch_bounds__(256) void ln2_kernel(const u16* __restrict__ y,
        const float* __restrict__ g0, const float* __restrict__ b0,
        const float* __restrict__ g1, const float* __restrict__ b1,
        u16* __restrict__ seq) {
    __shared__ float sred[4];
    int n = blockIdx.x, t = threadIdx.x;
    int modality = n >> 13, node = n & (NN - 1);
    const float* g = modality ? g1 : g0;
    const float* b = modality ? b1 : b0;
    const u16* yr = y + (size_t)n * DD;
    float x0 = bf2f(yr[t]), x1 = bf2f(yr[t + 256]);
    float s = x0 + x1;
    for (int off = 32; off; off >>= 1) s += __shfl_xor(s, off);
    if ((t & 63) == 0) sred[t >> 6] = s;
    __syncthreads();
    float mean = (sred[0] + sred[1] + sred[2] + sred[3]) * (1.0f / DD);
    __syncthreads();
    float d0 = x0 - mean, d1 = x1 - mean;
    float vs = d0 * d0 + d1 * d1;
    for (int off = 32; off; off >>= 1) vs += __shfl_xor(vs, off);
    if ((t & 63) == 0) sred[t >> 6] = vs;
    __syncthreads();
    float var = (sred[0] + sred[1] + sred[2] + sred[3]) * (1.0f / DD);
    float inv = rsqrtf(var + 1e-5f);
    u16* out = seq + (size_t)node * (2 * DD) + modality * DD;
    out[t]       = f2bf(d0 * inv * g[t]       + b[t]);
    out[t + 256] = f2bf(d1 * inv * g[t + 256] + b[t + 256]);
}

// MHA over 2 tokens, 8 heads of 64. One wave per (node, head). ctxm = mean_t(ctx_t).
__global__ __launch_bounds__(256) void attn_kernel(const u16* __restrict__ qkv,
        u16* __restrict__ ctxm) {
    int gid = blockIdx.x * 4 + (threadIdx.x >> 6);
    int lane = threadIdx.x & 63;
    int n = gid >> 3, h = gid & 7;
    const u16* r0 = qkv + (size_t)(n * 2) * 1536;
    const u16* r1 = r0 + 1536;
    float q0 = bf2f(r0[h * 64 + lane]);
    float k0 = bf2f(r0[512 + h * 64 + lane]);
    float v0 = bf2f(r0[1024 + h * 64 + lane]);
    float q1 = bf2f(r1[h * 64 + lane]);
    float k1 = bf2f(r1[512 + h * 64 + lane]);
    float v1 = bf2f(r1[1024 + h * 64 + lane]);
    float p00 = q0 * k0, p01 = q0 * k1, p10 = q1 * k0, p11 = q1 * k1;
    for (int off = 32; off; off >>= 1) {
        p00 += __shfl_xor(p00, off);
        p01 += __shfl_xor(p01, off);
        p10 += __shfl_xor(p10, off);
        p11 += __shfl_xor(p11, off);
    }
    const float sc = 0.125f;  // 1/sqrt(64)
    float s00 = p00 * sc, s01 = p01 * sc, s10 = p10 * sc, s11 = p11 * sc;
    float m0 = fmaxf(s00, s01), e00 = __expf(s00 - m0), e01 = __expf(s01 - m0);
    float a00 = e00 / (e00 + e01), a01 = e01 / (e00 + e01);
    float m1 = fmaxf(s10, s11), e10 = __expf(s10 - m1), e11 = __expf(s11 - m1);
    float a10 = e10 / (e10 + e11), a11 = e11 / (e10 + e11);
    float c0 = a00 * v0 + a01 * v1;
    float c1 = a10 * v0 + a11 * v1;
    ctxm[(size_t)n * 512 + h * 64 + lane] = f2bf(0.5f * (c0 + c1));
}

// Top-16 + softmax stats over bf16 S. ONE WAVE PER ROW, streaming.
__global__ __launch_bounds__(256) void topk_bf16(const u16* __restrict__ S,
        float* __restrict__ topv, int* __restrict__ topi) {
    const float NEG = -3e38f;
    int row = blockIdx.x * 4 + (threadIdx.x >> 6);
    int lane = threadIdx.x & 63;
    const u16* Sr = S + (size_t)row * NN;

    float m = NEG, l = 0.0f;
    float t1v = NEG, t2v = NEG;
    int t1i = 0x7FFFFFFF, t2i = 0x7FFFFFFF;

    #pragma unroll
    for (int p = 0; p < 16; ++p) {
        uint4 raw = *(const uint4*)(Sr + p * 512 + lane * 8);
        int base = p * 512 + lane * 8;
        #pragma unroll
        for (int q = 0; q < 4; ++q) {
            unsigned w = (&raw.x)[q];
            #pragma unroll
            for (int h = 0; h < 2; ++h) {
                float x = h ? bfhi(w) : bflo(w);
                int xi = base + q * 2 + h;
                if (x > m) { l = l * __expf(m - x) + 1.0f; m = x; }
                else l += __expf(x - m);
                bool g1 = x > t1v, g2 = x > t2v;
                t2v = g1 ? t1v : (g2 ? x : t2v);
                t2i = g1 ? t1i : (g2 ? xi : t2i);
                t1v = g1 ? x : t1v;
                t1i = g1 ? xi : t1i;
            }
        }
    }
    #pragma unroll
    for (int off = 32; off; off >>= 1) {
        float om = __shfl_xor(m, off);
        float ol = __shfl_xor(l, off);
        float nm = fmaxf(m, om);
        l = l * __expf(m - nm) + ol * __expf(om - nm);
        m = nm;
    }

    unsigned mk0 = 0, mk1 = 0, mk2 = 0, mk3 = 0;
    float cv = t1v; int ci = t1i;
    float bv = t2v; int bi = t2i;
    for (int r = 0; r < 16; ++r) {
        float wv = cv; int wi = ci;
        #pragma unroll
        for (int off = 32; off; off >>= 1) {
            float ov = __shfl_xor(wv, off);
            int oi = __shfl_xor(wi, off);
            if (ov > wv || (ov == wv && oi < wi)) { wv = ov; wi = oi; }
        }
        if (lane == 0) {
            topv[(size_t)row * 16 + r] = __expf(wv - m) / l;
            topi[(size_t)row * 16 + r] = wi;
        }
        if (wi == ci) {
            int slot = ((wi >> 9) << 3) | (wi & 7);
            unsigned bit = 1u << (slot & 31);
            if (slot < 32) mk0 |= bit; else if (slot < 64) mk1 |= bit;
            else if (slot < 96) mk2 |= bit; else mk3 |= bit;
            cv = bv; ci = bi;
            bv = NEG; bi = 0x7FFFFFFF;
            if (ci == 0x7FFFFFFF) {
                float nb = NEG; int ni = 0x7FFFFFFF;
                #pragma unroll
                for (int p = 0; p < 16; ++p) {
                    uint4 raw = *(const uint4*)(Sr + p * 512 + lane * 8);
                    int base = p * 512 + lane * 8;
                    #pragma unroll
                    for (int q = 0; q < 4; ++q) {
                        unsigned w = (&raw.x)[q];
                        #pragma unroll
                        for (int h = 0; h < 2; ++h) {
                            int sl = p * 8 + q * 2 + h;
                            unsigned mw = (sl < 32) ? mk0 : (sl < 64) ? mk1
                                        : (sl < 96) ? mk2 : mk3;
                            float x = ((mw >> (sl & 31)) & 1u) ? NEG
                                    : (h ? bfhi(w) : bflo(w));
                            if (x > nb) { nb = x; ni = base + q * 2 + h; }
                        }
                    }
                }
                cv = nb; ci = ni;
            }
        }
    }
}

// Fused scatter + diag (exact ref semantics, race-free).
__global__ __launch_bounds__(256) void scatter_diag(const float* __restrict__ topv,
        const int* __restrict__ topi, float* __restrict__ H) {
    int tk = blockIdx.x * 256 + threadIdx.x;  // 544 * 256 = 139264
    if (tk < NN * 16) {
        int i = tk >> 4;
        int idx = topi[tk];
        H[(size_t)idx * NN + i] = topv[tk];
    } else {
        int c = tk - NN * 16;
        const int* ti = topi + c * 16;
        bool self = false;
        #pragma unroll
        for (int j = 0; j < 16; ++j) self |= (ti[j] == c);
        if (!self) H[(size_t)c * NN + c] = 1.0f;
    }
}

// ew = max(sigmoid(hidden @ w2 + b2), 1e-8), fp32 out. One wave per node.
__global__ __launch_bounds__(256) void ew_kernel(const u16* __restrict__ hidden,
        const float* __restrict__ w2, const float* __restrict__ b2, float* __restrict__ out) {
    int n = blockIdx.x * 4 + (threadIdx.x >> 6);
    int lane = threadIdx.x & 63;
    const u16* hr = hidden + (size_t)n * 256;
    float s = 0.0f;
    #pragma unroll
    for (int p = 0; p < 4; ++p) s += bf2f(hr[lane + p * 64]) * w2[lane + p * 64];
    for (int off = 32; off; off >>= 1) s += __shfl_xor(s, off);
    if (lane == 0) {
        float z = s + b2[0];
        float sig = 1.0f / (1.0f + __expf(-z));
        out[n] = fmaxf(sig, 1e-8f);
    }
}

extern "C" void kernel_launch(void* const* d_in, const int* in_sizes, int n_in,
                              void* d_out, int out_size, void* d_ws, size_t ws_size,
                              hipStream_t stream) {
    const float* x0    = (const float*)d_in[0];
    const float* x1    = (const float*)d_in[1];
    const float* w_p0  = (const float*)d_in[2];
    const float* b_p0  = (const float*)d_in[3];
    const float* g0    = (const float*)d_in[4];
    const float* beta0 = (const float*)d_in[5];
    const float* w_p1  = (const float*)d_in[6];
    const float* b_p1  = (const float*)d_in[7];
    const float* g1    = (const float*)d_in[8];
    const float* beta1 = (const float*)d_in[9];
    const float* in_w  = (const float*)d_in[10];
    const float* in_b  = (const float*)d_in[11];
    const float* out_w = (const float*)d_in[12];
    const float* out_b = (const float*)d_in[13];
    const float* ew_w1 = (const float*)d_in[14];
    const float* ew_b1 = (const float*)d_in[15];
    const float* ew_w2 = (const float*)d_in[16];
    const float* ew_b2 = (const float*)d_in[17];

    float* Hf = (float*)d_out;                  // [8192][8192] fp32 (256 MB)
    float* ew_out = Hf + (size_t)NN * NN;       // [8192] fp32

    // bf16 staging inside the fp32 H region (dead before memset rewrites H).
    u16* Hu = (u16*)d_out;
    u16* x0b    = Hu;                           //   0.. 8 MB  (x0b||x1b contiguous)
    u16* x1b    = Hu + 4194304;                 //   8..16 MB
    u16* y01    = Hu + 8388608;                 //  16..32 MB  [16384][512]
    u16* seq    = Hu + 16777216;                //  32..48 MB  [8192][2][512]
    u16* qkv    = Hu + 25165824;                //  48..96 MB  [16384][1536]
    u16* ctxm   = Hu + 50331648;                //  96..104 MB
    u16* hidden = Hu + 54525952;                // 104..108 MB [8192][256]
    u16* wp0b   = Hu + 60817408;                // 116 MB.. weights (3.25 MB)
    u16* wp1b   = wp0b + 262144;
    u16* inwb   = wp1b + 262144;                // [1536][512]
    u16* outwb  = inwb + 786432;
    u16* eww1b  = outwb + 262144;               // [256][512]
    u16* Sb     = Hu + 67108864;                // 128..256 MB raw scores bf16
    // ws: survives the S GEMM (9 MB)
    char* ws = (char*)d_ws;
    u16* fusedB = (u16*)ws;                     // [8192][512] bf16
    float* topv = (float*)(ws + (8u << 20));
    int*   topi = (int*)(ws + (8u << 20) + 524288);

    dim3 blk(256);
    const int BIG = 1 << 30;
    // 0: fp32 -> bf16 for all MFMA operands
    cvt7<<<dim3(4928), blk, 0, stream>>>(x0, x0b, x1, x1b, w_p0, wp0b, w_p1, wp1b,
                                         in_w, inwb, out_w, outwb, ew_w1, eww1b);
    // 1: both modality projections in one launch
    gemm_bt<true, true, true><<<dim3(4, 128), blk, 0, stream>>>(
        x0b, wp0b, b_p0, wp1b, b_p1, 64, y01, 2 * NN, DD, DD);
    // 2: fused LayerNorm -> seq
    ln2_kernel<<<dim3(2 * NN), blk, 0, stream>>>(y01, g0, beta0, g1, beta1, seq);
    // 3: qkv = seq @ in_w^T + in_b
    gemm_bt<false, true, false><<<dim3(12, 128), blk, 0, stream>>>(
        seq, inwb, in_b, nullptr, nullptr, BIG, qkv, 2 * NN, 1536, DD);
    // 4: attention -> ctxm
    attn_kernel<<<dim3(NN * 8 / 4), blk, 0, stream>>>(qkv, ctxm);
    // 5: fused = ctxm @ out_w^T + out_b
    gemm_bt<false, true, false><<<dim3(4, 64), blk, 0, stream>>>(
        ctxm, outwb, out_b, nullptr, nullptr, BIG, fusedB, NN, DD, DD);
    // 6: hidden = relu(fused @ ew_w1^T + ew_b1)
    gemm_bt<true, true, false><<<dim3(2, 64), blk, 0, stream>>>(
        fusedB, eww1b, ew_b1, nullptr, nullptr, BIG, hidden, NN, 256, DD);
    // 7: ew
    ew_kernel<<<dim3(NN / 4), blk, 0, stream>>>(hidden, ew_w2, ew_b2, ew_out);
    // 8: S = fused @ fused^T (bf16), symmetric: upper-tri blocks + dual store
    gemm_sym<<<dim3(64, 64), blk, 0, stream>>>(fusedB, Sb);
    // 9: top-16 + softmax stats
    topk_bf16<<<dim3(NN / 4), blk, 0, stream>>>(Sb, topv, topi);
    // 10: H := 0 (fast fill path)
    hipMemsetAsync(Hf, 0, (size_t)NN * NN * sizeof(float), stream);
    // 11: fused scatter + conditional diag
    scatter_diag<<<dim3((NN * 16 + NN) / 256), blk, 0, stream>>>(topv, topi, Hf);
}

// Round 13
// 687.937 us; speedup vs baseline: 1.0348x; 1.0043x over previous
//
#include <hip/hip_runtime.h>
#include <hip/hip_bf16.h>

#define NN 8192
#define DD 512

typedef unsigned short u16;
typedef __bf16 bf16_t;
typedef bf16_t bf16x8 __attribute__((ext_vector_type(8)));
typedef float f32x4 __attribute__((ext_vector_type(4)));

__device__ __forceinline__ float bf2f(u16 h) {
    union { unsigned u; float f; } v; v.u = ((unsigned)h) << 16; return v.f;
}
__device__ __forceinline__ float bflo(unsigned u) {
    union { unsigned u; float f; } v; v.u = u << 16; return v.f;
}
__device__ __forceinline__ float bfhi(unsigned u) {
    union { unsigned u; float f; } v; v.u = u & 0xFFFF0000u; return v.f;
}
__device__ __forceinline__ u16 f2bf(float f) {
    union { float f; unsigned u; } v; v.f = f;
    unsigned r = v.u + 0x7fffu + ((v.u >> 16) & 1u);
    return (u16)(r >> 16);
}

// Fused fp32->bf16 convert of the 7 GEMM operands, 8 elems/thread.
__global__ __launch_bounds__(256) void cvt7(
        const float* __restrict__ s0, u16* __restrict__ d0,
        const float* __restrict__ s1, u16* __restrict__ d1,
        const float* __restrict__ s2, u16* __restrict__ d2,
        const float* __restrict__ s3, u16* __restrict__ d3,
        const float* __restrict__ s4, u16* __restrict__ d4,
        const float* __restrict__ s5, u16* __restrict__ d5,
        const float* __restrict__ s6, u16* __restrict__ d6) {
    size_t v = ((size_t)blockIdx.x * 256 + threadIdx.x) * 8;
    const float* s; u16* d; size_t off;
    if (v < 4194304)      { s = s0; d = d0; off = v; }
    else if (v < 8388608) { s = s1; d = d1; off = v - 4194304; }
    else if (v < 8650752) { s = s2; d = d2; off = v - 8388608; }
    else if (v < 8912896) { s = s3; d = d3; off = v - 8650752; }
    else if (v < 9699328) { s = s4; d = d4; off = v - 8912896; }
    else if (v < 9961472) { s = s5; d = d5; off = v - 9699328; }
    else                  { s = s6; d = d6; off = v - 9961472; }
    float4 a = *(const float4*)(s + off);
    float4 b = *(const float4*)(s + off + 4);
    ushort4 o0 = make_ushort4(f2bf(a.x), f2bf(a.y), f2bf(a.z), f2bf(a.w));
    ushort4 o1 = make_ushort4(f2bf(b.x), f2bf(b.y), f2bf(b.z), f2bf(b.w));
    *(ushort4*)(d + off) = o0;
    *(ushort4*)(d + off + 4) = o1;
}

// C[M][Nc] = act(A[M][K] @ B[Nc][K]^T + bias), bf16 in/out, fp32 accum/bias.
// m97-class async staging, 128x128 tile, BK=64, 4 waves (2x2), 4x4 MFMA 16x16x32.
// LDS-swizzled coalesced epilogue. SPLIT: blocks y >= halfY use B2/bias2.
#define EPS_LDS 136
template<bool RELU, bool BIAS, bool SPLIT>
__global__ __launch_bounds__(256) void gemm_bt(const u16* __restrict__ A,
        const u16* __restrict__ B, const float* __restrict__ bias,
        const u16* __restrict__ B2, const float* __restrict__ bias2, int halfY,
        u16* __restrict__ C, int M, int Nc, int K) {
    __shared__ alignas(16) u16 Smem[128 * EPS_LDS];
    u16* As = Smem;
    u16* Bs = Smem + 128 * 64;
    const int t = threadIdx.x;
    const int lane = t & 63;
    const int wave = t >> 6;
    const int wm = (wave >> 1) * 64;
    const int wn = (wave & 1) * 64;
    const int rowA = blockIdx.y * 128;
    const int rowB = blockIdx.x * 128;
    if (SPLIT && (int)blockIdx.y >= halfY) { B = B2; bias = bias2; }

    f32x4 acc[4][4] = {};
    const int mrow = lane & 15;
    const int kk = (lane >> 4) * 8;

    for (int k0 = 0; k0 < K; k0 += 64) {
        __syncthreads();
        #pragma unroll
        for (int r = 0; r < 4; ++r) {
            int chunk = r * 256 + t;
            const u16* srcA = A + (size_t)(rowA + (chunk >> 3)) * K + k0 + (chunk & 7) * 8;
            __builtin_amdgcn_global_load_lds(
                (const __attribute__((address_space(1))) void*)srcA,
                (__attribute__((address_space(3))) void*)(As + chunk * 8), 16, 0, 0);
            const u16* srcB = B + (size_t)(rowB + (chunk >> 3)) * K + k0 + (chunk & 7) * 8;
            __builtin_amdgcn_global_load_lds(
                (const __attribute__((address_space(1))) void*)srcB,
                (__attribute__((address_space(3))) void*)(Bs + chunk * 8), 16, 0, 0);
        }
        __syncthreads();
        #pragma unroll
        for (int ks = 0; ks < 64; ks += 32) {
            bf16x8 af[4], bfv[4];
            #pragma unroll
            for (int i = 0; i < 4; ++i)
                af[i] = *(const bf16x8*)(As + (wm + i * 16 + mrow) * 64 + ks + kk);
            #pragma unroll
            for (int j = 0; j < 4; ++j)
                bfv[j] = *(const bf16x8*)(Bs + (wn + j * 16 + mrow) * 64 + ks + kk);
            #pragma unroll
            for (int i = 0; i < 4; ++i)
                #pragma unroll
                for (int j = 0; j < 4; ++j)
                    acc[i][j] = __builtin_amdgcn_mfma_f32_16x16x32_bf16(af[i], bfv[j], acc[i][j], 0, 0, 0);
        }
    }

    __syncthreads();
    const int er0 = wm + (lane >> 4) * 4;
    const int ec0 = wn + (lane & 15);
    #pragma unroll
    for (int j = 0; j < 4; ++j) {
        int c = ec0 + j * 16;
        float bv = BIAS ? bias[rowB + c] : 0.0f;
        #pragma unroll
        for (int i = 0; i < 4; ++i) {
            #pragma unroll
            for (int r = 0; r < 4; ++r) {
                float v = acc[i][j][r] + bv;
                if (RELU) v = fmaxf(v, 0.0f);
                Smem[(er0 + i * 16 + r) * EPS_LDS + c] = f2bf(v);
            }
        }
    }
    __syncthreads();
    #pragma unroll
    for (int pass = 0; pass < 8; ++pass) {
        int chunk = pass * 256 + t;
        int rloc = chunk >> 4, coff = (chunk & 15) * 8;
        bf16x8 v = *(const bf16x8*)(Smem + rloc * EPS_LDS + coff);
        *(bf16x8*)(C + (size_t)(rowA + rloc) * Nc + rowB + coff) = v;
    }
}

// qkv GEMM with fused QK->score epilogue. A = seq [16384][512], B = in_w [1536][512].
// Block c = blockIdx.x: c<8 -> head c: tile cols = {q dims c*64..+64, k dims 512+c*64..+64};
// epilogue computes s_ts = 0.125 * dot64(q_t, k_s) -> scores[node][c][4] fp32 (no QK store).
// c>=8 -> V cols [1024+(c-8)*128 ..+128), stored to V[16384][512].
__global__ __launch_bounds__(256) void gemm_qkv(const u16* __restrict__ A,
        const u16* __restrict__ B, const float* __restrict__ bias,
        u16* __restrict__ V, float* __restrict__ scores) {
    __shared__ alignas(16) u16 Smem[128 * EPS_LDS];
    u16* As = Smem;
    u16* Bs = Smem + 128 * 64;
    const int t = threadIdx.x;
    const int lane = t & 63;
    const int wave = t >> 6;
    const int wm = (wave >> 1) * 64;
    const int wn = (wave & 1) * 64;
    const int c = blockIdx.x;
    const int rowA = blockIdx.y * 128;
    const bool isQK = (c < 8);

    f32x4 acc[4][4] = {};
    const int mrow = lane & 15;
    const int kk = (lane >> 4) * 8;

    for (int k0 = 0; k0 < DD; k0 += 64) {
        __syncthreads();
        #pragma unroll
        for (int r = 0; r < 4; ++r) {
            int chunk = r * 256 + t;
            int rr = chunk >> 3;
            // B-row map: QK strips or V slab
            int brow = isQK ? (c * 64 + rr + ((rr >= 64) ? 448 : 0))
                            : (1024 + (c - 8) * 128 + rr);
            const u16* srcA = A + (size_t)(rowA + rr) * DD + k0 + (chunk & 7) * 8;
            __builtin_amdgcn_global_load_lds(
                (const __attribute__((address_space(1))) void*)srcA,
                (__attribute__((address_space(3))) void*)(As + chunk * 8), 16, 0, 0);
            const u16* srcB = B + (size_t)brow * DD + k0 + (chunk & 7) * 8;
            __builtin_amdgcn_global_load_lds(
                (const __attribute__((address_space(1))) void*)srcB,
                (__attribute__((address_space(3))) void*)(Bs + chunk * 8), 16, 0, 0);
        }
        __syncthreads();
        #pragma unroll
        for (int ks = 0; ks < 64; ks += 32) {
            bf16x8 af[4], bfv[4];
            #pragma unroll
            for (int i = 0; i < 4; ++i)
                af[i] = *(const bf16x8*)(As + (wm + i * 16 + mrow) * 64 + ks + kk);
            #pragma unroll
            for (int j = 0; j < 4; ++j)
                bfv[j] = *(const bf16x8*)(Bs + (wn + j * 16 + mrow) * 64 + ks + kk);
            #pragma unroll
            for (int i = 0; i < 4; ++i)
                #pragma unroll
                for (int j = 0; j < 4; ++j)
                    acc[i][j] = __builtin_amdgcn_mfma_f32_16x16x32_bf16(af[i], bfv[j], acc[i][j], 0, 0, 0);
        }
    }

    __syncthreads();
    const int er0 = wm + (lane >> 4) * 4;
    const int ec0 = wn + (lane & 15);
    #pragma unroll
    for (int j = 0; j < 4; ++j) {
        int cc = ec0 + j * 16;
        int bcol = isQK ? ((cc < 64) ? c * 64 + cc : 448 + c * 64 + cc)
                        : (1024 + (c - 8) * 128 + cc);
        float bv = bias[bcol];
        #pragma unroll
        for (int i = 0; i < 4; ++i) {
            #pragma unroll
            for (int r = 0; r < 4; ++r)
                Smem[(er0 + i * 16 + r) * EPS_LDS + cc] = f2bf(acc[i][j][r] + bv);
        }
    }
    __syncthreads();
    if (isQK) {
        // thread -> (node nd in tile, combo ts): s_ts = 0.125 * sum_d q[2nd+t][d]*k[2nd+s][d]
        int nd = t >> 2, cb = t & 3, tt = cb >> 1, ss = cb & 1;
        const u16* qrow = Smem + (2 * nd + tt) * EPS_LDS;
        const u16* krow = Smem + (2 * nd + ss) * EPS_LDS + 64;
        float s = 0.0f;
        #pragma unroll
        for (int d8 = 0; d8 < 8; ++d8) {
            bf16x8 qv = *(const bf16x8*)(qrow + d8 * 8);
            bf16x8 kv = *(const bf16x8*)(krow + d8 * 8);
            #pragma unroll
            for (int u = 0; u < 8; ++u) s += (float)qv[u] * (float)kv[u];
        }
        scores[(size_t)(rowA / 2 + nd) * 32 + c * 4 + cb] = s * 0.125f;
    } else {
        #pragma unroll
        for (int pass = 0; pass < 8; ++pass) {
            int chunk = pass * 256 + t;
            int rloc = chunk >> 4, coff = (chunk & 15) * 8;
            bf16x8 v = *(const bf16x8*)(Smem + rloc * EPS_LDS + coff);
            *(bf16x8*)(V + (size_t)(rowA + rloc) * 512 + (c - 8) * 128 + coff) = v;
        }
    }
}

// Symmetric S = F @ F^T (bf16). Upper-triangle blocks; off-diag stores twice.
#define SYM_LDS 129
__global__ __launch_bounds__(256) void gemm_sym(const u16* __restrict__ F,
        u16* __restrict__ C) {
    __shared__ alignas(16) u16 Smem[128 * SYM_LDS];
    const int bx = blockIdx.x, by = blockIdx.y;
    if (bx < by) return;
    u16* As = Smem;
    u16* Bs = Smem + 128 * 64;
    const int t = threadIdx.x;
    const int lane = t & 63;
    const int wave = t >> 6;
    const int wm = (wave >> 1) * 64;
    const int wn = (wave & 1) * 64;
    const int rowI = by * 128;
    const int rowJ = bx * 128;

    f32x4 acc[4][4] = {};
    const int mrow = lane & 15;
    const int kk = (lane >> 4) * 8;

    for (int k0 = 0; k0 < DD; k0 += 64) {
        __syncthreads();
        #pragma unroll
        for (int r = 0; r < 4; ++r) {
            int chunk = r * 256 + t;
            const u16* srcA = F + (size_t)(rowI + (chunk >> 3)) * DD + k0 + (chunk & 7) * 8;
            __builtin_amdgcn_global_load_lds(
                (const __attribute__((address_space(1))) void*)srcA,
                (__attribute__((address_space(3))) void*)(As + chunk * 8), 16, 0, 0);
            const u16* srcB = F + (size_t)(rowJ + (chunk >> 3)) * DD + k0 + (chunk & 7) * 8;
            __builtin_amdgcn_global_load_lds(
                (const __attribute__((address_space(1))) void*)srcB,
                (__attribute__((address_space(3))) void*)(Bs + chunk * 8), 16, 0, 0);
        }
        __syncthreads();
        #pragma unroll
        for (int ks = 0; ks < 64; ks += 32) {
            bf16x8 af[4], bfv[4];
            #pragma unroll
            for (int i = 0; i < 4; ++i)
                af[i] = *(const bf16x8*)(As + (wm + i * 16 + mrow) * 64 + ks + kk);
            #pragma unroll
            for (int j = 0; j < 4; ++j)
                bfv[j] = *(const bf16x8*)(Bs + (wn + j * 16 + mrow) * 64 + ks + kk);
            #pragma unroll
            for (int i = 0; i < 4; ++i)
                #pragma unroll
                for (int j = 0; j < 4; ++j)
                    acc[i][j] = __builtin_amdgcn_mfma_f32_16x16x32_bf16(af[i], bfv[j], acc[i][j], 0, 0, 0);
        }
    }

    __syncthreads();
    const int er0 = wm + (lane >> 4) * 4;
    const int ec0 = wn + (lane & 15);
    #pragma unroll
    for (int j = 0; j < 4; ++j) {
        int c = ec0 + j * 16;
        #pragma unroll
        for (int i = 0; i < 4; ++i) {
            #pragma unroll
            for (int r = 0; r < 4; ++r)
                Smem[(er0 + i * 16 + r) * SYM_LDS + c] = f2bf(acc[i][j][r]);
        }
    }
    __syncthreads();
    #pragma unroll
    for (int pass = 0; pass < 8; ++pass) {
        int chunk = pass * 256 + t;
        int rloc = chunk >> 4, coff = (chunk & 15) * 8;
        union { u16 us[8]; bf16x8 v; } buf;
        #pragma unroll
        for (int k = 0; k < 8; ++k) buf.us[k] = Smem[rloc * SYM_LDS + coff + k];
        *(bf16x8*)(C + (size_t)(rowI + rloc) * NN + rowJ + coff) = buf.v;
    }
    if (bx != by) {
        #pragma unroll
        for (int pass = 0; pass < 8; ++pass) {
            int chunk = pass * 256 + t;
            int tr = chunk >> 4, roff = (chunk & 15) * 8;
            union { u16 us[8]; bf16x8 v; } buf;
            #pragma unroll
            for (int k = 0; k < 8; ++k) buf.us[k] = Smem[(roff + k) * SYM_LDS + tr];
            *(bf16x8*)(C + (size_t)(rowJ + tr) * NN + rowI + roff) = buf.v;
        }
    }
}

// Fused LayerNorm over D=512 for BOTH modalities; y = [y0;y1] (16384 rows).
__global__ __launch_bounds__(256) void ln2_kernel(const u16* __restrict__ y,
        const float* __restrict__ g0, const float* __restrict__ b0,
        const float* __restrict__ g1, const float* __restrict__ b1,
        u16* __restrict__ seq) {
    __shared__ float sred[4];
    int n = blockIdx.x, t = threadIdx.x;
    int modality = n >> 13, node = n & (NN - 1);
    const float* g = modality ? g1 : g0;
    const float* b = modality ? b1 : b0;
    const u16* yr = y + (size_t)n * DD;
    float x0 = bf2f(yr[t]), x1 = bf2f(yr[t + 256]);
    float s = x0 + x1;
    for (int off = 32; off; off >>= 1) s += __shfl_xor(s, off);
    if ((t & 63) == 0) sred[t >> 6] = s;
    __syncthreads();
    float mean = (sred[0] + sred[1] + sred[2] + sred[3]) * (1.0f / DD);
    __syncthreads();
    float d0 = x0 - mean, d1 = x1 - mean;
    float vs = d0 * d0 + d1 * d1;
    for (int off = 32; off; off >>= 1) vs += __shfl_xor(vs, off);
    if ((t & 63) == 0) sred[t >> 6] = vs;
    __syncthreads();
    float var = (sred[0] + sred[1] + sred[2] + sred[3]) * (1.0f / DD);
    float inv = rsqrtf(var + 1e-5f);
    u16* out = seq + (size_t)node * (2 * DD) + modality * DD;
    out[t]       = f2bf(d0 * inv * g[t]       + b[t]);
    out[t + 256] = f2bf(d1 * inv * g[t + 256] + b[t + 256]);
}

// V-weighting from fused scores: ctxm = a0*v0 + a1*v1 (a_s = 0.5*sum_t softmax_ts).
// One wave per node; lane covers dims [lane*8, lane*8+8), head = lane>>3.
__global__ __launch_bounds__(256) void attn_v(const float* __restrict__ scores,
        const u16* __restrict__ V, u16* __restrict__ ctxm) {
    int n = blockIdx.x * 4 + (threadIdx.x >> 6);
    int lane = threadIdx.x & 63;
    int h = lane >> 3;
    float4 sc = *(const float4*)(scores + (size_t)n * 32 + h * 4);
    float s00 = sc.x, s01 = sc.y, s10 = sc.z, s11 = sc.w;
    float m0 = fmaxf(s00, s01), e00 = __expf(s00 - m0), e01 = __expf(s01 - m0);
    float a00 = e00 / (e00 + e01), a01 = e01 / (e00 + e01);
    float m1 = fmaxf(s10, s11), e10 = __expf(s10 - m1), e11 = __expf(s11 - m1);
    float a10 = e10 / (e10 + e11), a11 = e11 / (e10 + e11);
    float al0 = 0.5f * (a00 + a10), al1 = 0.5f * (a01 + a11);
    bf16x8 v0 = *(const bf16x8*)(V + (size_t)(2 * n) * 512 + lane * 8);
    bf16x8 v1 = *(const bf16x8*)(V + (size_t)(2 * n + 1) * 512 + lane * 8);
    union { u16 us[8]; bf16x8 v; } o;
    #pragma unroll
    for (int u = 0; u < 8; ++u)
        o.us[u] = f2bf(al0 * (float)v0[u] + al1 * (float)v1[u]);
    *(bf16x8*)(ctxm + (size_t)n * 512 + lane * 8) = o.v;
}

// Top-16 + softmax stats over bf16 S. ONE WAVE PER ROW, streaming.
__global__ __launch_bounds__(256) void topk_bf16(const u16* __restrict__ S,
        float* __restrict__ topv, int* __restrict__ topi) {
    const float NEG = -3e38f;
    int row = blockIdx.x * 4 + (threadIdx.x >> 6);
    int lane = threadIdx.x & 63;
    const u16* Sr = S + (size_t)row * NN;

    float m = NEG, l = 0.0f;
    float t1v = NEG, t2v = NEG;
    int t1i = 0x7FFFFFFF, t2i = 0x7FFFFFFF;

    #pragma unroll
    for (int p = 0; p < 16; ++p) {
        uint4 raw = *(const uint4*)(Sr + p * 512 + lane * 8);
        int base = p * 512 + lane * 8;
        #pragma unroll
        for (int q = 0; q < 4; ++q) {
            unsigned w = (&raw.x)[q];
            #pragma unroll
            for (int h = 0; h < 2; ++h) {
                float x = h ? bfhi(w) : bflo(w);
                int xi = base + q * 2 + h;
                if (x > m) { l = l * __expf(m - x) + 1.0f; m = x; }
                else l += __expf(x - m);
                bool g1 = x > t1v, g2 = x > t2v;
                t2v = g1 ? t1v : (g2 ? x : t2v);
                t2i = g1 ? t1i : (g2 ? xi : t2i);
                t1v = g1 ? x : t1v;
                t1i = g1 ? xi : t1i;
            }
        }
    }
    #pragma unroll
    for (int off = 32; off; off >>= 1) {
        float om = __shfl_xor(m, off);
        float ol = __shfl_xor(l, off);
        float nm = fmaxf(m, om);
        l = l * __expf(m - nm) + ol * __expf(om - nm);
        m = nm;
    }

    unsigned mk0 = 0, mk1 = 0, mk2 = 0, mk3 = 0;
    float cv = t1v; int ci = t1i;
    float bv = t2v; int bi = t2i;
    for (int r = 0; r < 16; ++r) {
        float wv = cv; int wi = ci;
        #pragma unroll
        for (int off = 32; off; off >>= 1) {
            float ov = __shfl_xor(wv, off);
            int oi = __shfl_xor(wi, off);
            if (ov > wv || (ov == wv && oi < wi)) { wv = ov; wi = oi; }
        }
        if (lane == 0) {
            topv[(size_t)row * 16 + r] = __expf(wv - m) / l;
            topi[(size_t)row * 16 + r] = wi;
        }
        if (wi == ci) {
            int slot = ((wi >> 9) << 3) | (wi & 7);
            unsigned bit = 1u << (slot & 31);
            if (slot < 32) mk0 |= bit; else if (slot < 64) mk1 |= bit;
            else if (slot < 96) mk2 |= bit; else mk3 |= bit;
            cv = bv; ci = bi;
            bv = NEG; bi = 0x7FFFFFFF;
            if (ci == 0x7FFFFFFF) {
                float nb = NEG; int ni = 0x7FFFFFFF;
                #pragma unroll
                for (int p = 0; p < 16; ++p) {
                    uint4 raw = *(const uint4*)(Sr + p * 512 + lane * 8);
                    int base = p * 512 + lane * 8;
                    #pragma unroll
                    for (int q = 0; q < 4; ++q) {
                        unsigned w = (&raw.x)[q];
                        #pragma unroll
                        for (int h = 0; h < 2; ++h) {
                            int sl = p * 8 + q * 2 + h;
                            unsigned mw = (sl < 32) ? mk0 : (sl < 64) ? mk1
                                        : (sl < 96) ? mk2 : mk3;
                            float x = ((mw >> (sl & 31)) & 1u) ? NEG
                                    : (h ? bfhi(w) : bflo(w));
                            if (x > nb) { nb = x; ni = base + q * 2 + h; }
                        }
                    }
                }
                cv = nb; ci = ni;
            }
        }
    }
}

// Fused scatter + diag (exact ref semantics, race-free).
__global__ __launch_bounds__(256) void scatter_diag(const float* __restrict__ topv,
        const int* __restrict__ topi, float* __restrict__ H) {
    int tk = blockIdx.x * 256 + threadIdx.x;
    if (tk < NN * 16) {
        int i = tk >> 4;
        int idx = topi[tk];
        H[(size_t)idx * NN + i] = topv[tk];
    } else {
        int c = tk - NN * 16;
        const int* ti = topi + c * 16;
        bool self = false;
        #pragma unroll
        for (int j = 0; j < 16; ++j) self |= (ti[j] == c);
        if (!self) H[(size_t)c * NN + c] = 1.0f;
    }
}

// ew = max(sigmoid(hidden @ w2 + b2), 1e-8), fp32 out. One wave per node.
__global__ __launch_bounds__(256) void ew_kernel(const u16* __restrict__ hidden,
        const float* __restrict__ w2, const float* __restrict__ b2, float* __restrict__ out) {
    int n = blockIdx.x * 4 + (threadIdx.x >> 6);
    int lane = threadIdx.x & 63;
    const u16* hr = hidden + (size_t)n * 256;
    float s = 0.0f;
    #pragma unroll
    for (int p = 0; p < 4; ++p) s += bf2f(hr[lane + p * 64]) * w2[lane + p * 64];
    for (int off = 32; off; off >>= 1) s += __shfl_xor(s, off);
    if (lane == 0) {
        float z = s + b2[0];
        float sig = 1.0f / (1.0f + __expf(-z));
        out[n] = fmaxf(sig, 1e-8f);
    }
}

extern "C" void kernel_launch(void* const* d_in, const int* in_sizes, int n_in,
                              void* d_out, int out_size, void* d_ws, size_t ws_size,
                              hipStream_t stream) {
    const float* x0    = (const float*)d_in[0];
    const float* x1    = (const float*)d_in[1];
    const float* w_p0  = (const float*)d_in[2];
    const float* b_p0  = (const float*)d_in[3];
    const float* g0    = (const float*)d_in[4];
    const float* beta0 = (const float*)d_in[5];
    const float* w_p1  = (const float*)d_in[6];
    const float* b_p1  = (const float*)d_in[7];
    const float* g1    = (const float*)d_in[8];
    const float* beta1 = (const float*)d_in[9];
    const float* in_w  = (const float*)d_in[10];
    const float* in_b  = (const float*)d_in[11];
    const float* out_w = (const float*)d_in[12];
    const float* out_b = (const float*)d_in[13];
    const float* ew_w1 = (const float*)d_in[14];
    const float* ew_b1 = (const float*)d_in[15];
    const float* ew_w2 = (const float*)d_in[16];
    const float* ew_b2 = (const float*)d_in[17];

    float* Hf = (float*)d_out;                  // [8192][8192] fp32 (256 MB)
    float* ew_out = Hf + (size_t)NN * NN;       // [8192] fp32

    // bf16 staging inside the fp32 H region (dead before memset rewrites H).
    u16* Hu = (u16*)d_out;
    u16* x0b    = Hu;                           //   0.. 8 MB
    u16* x1b    = Hu + 4194304;                 //   8..16 MB
    u16* y01    = Hu + 8388608;                 //  16..32 MB  [16384][512]
    u16* seq    = Hu + 16777216;                //  32..48 MB  [8192][2][512]
    u16* Vbuf   = Hu + 25165824;                //  48..64 MB  [16384][512]
    u16* ctxm   = Hu + 50331648;                //  96..104 MB
    u16* hidden = Hu + 54525952;                // 104..108 MB [8192][256]
    float* scB  = (float*)(Hu + 58720256);      // 112..113 MB scores [8192][32] fp32
    u16* wp0b   = Hu + 60817408;                // 116 MB.. weights (3.25 MB)
    u16* wp1b   = wp0b + 262144;
    u16* inwb   = wp1b + 262144;                // [1536][512]
    u16* outwb  = inwb + 786432;
    u16* eww1b  = outwb + 262144;               // [256][512]
    u16* Sb     = Hu + 67108864;                // 128..256 MB raw scores bf16
    // ws: survives the S GEMM (9 MB)
    char* ws = (char*)d_ws;
    u16* fusedB = (u16*)ws;                     // [8192][512] bf16
    float* topv = (float*)(ws + (8u << 20));
    int*   topi = (int*)(ws + (8u << 20) + 524288);

    dim3 blk(256);
    const int BIG = 1 << 30;
    // 0: fp32 -> bf16 for all MFMA operands
    cvt7<<<dim3(4928), blk, 0, stream>>>(x0, x0b, x1, x1b, w_p0, wp0b, w_p1, wp1b,
                                         in_w, inwb, out_w, outwb, ew_w1, eww1b);
    // 1: both modality projections in one launch
    gemm_bt<true, true, true><<<dim3(4, 128), blk, 0, stream>>>(
        x0b, wp0b, b_p0, wp1b, b_p1, 64, y01, 2 * NN, DD, DD);
    // 2: fused LayerNorm -> seq
    ln2_kernel<<<dim3(2 * NN), blk, 0, stream>>>(y01, g0, beta0, g1, beta1, seq);
    // 3: qkv GEMM w/ fused QK->scores; V stored, Q/K never hit HBM
    gemm_qkv<<<dim3(12, 128), blk, 0, stream>>>(seq, inwb, in_b, Vbuf, scB);
    // 4: V-weighting -> ctxm
    attn_v<<<dim3(NN / 4), blk, 0, stream>>>(scB, Vbuf, ctxm);
    // 5: fused = ctxm @ out_w^T + out_b
    gemm_bt<false, true, false><<<dim3(4, 64), blk, 0, stream>>>(
        ctxm, outwb, out_b, nullptr, nullptr, BIG, fusedB, NN, DD, DD);
    // 6: hidden = relu(fused @ ew_w1^T + ew_b1)
    gemm_bt<true, true, false><<<dim3(2, 64), blk, 0, stream>>>(
        fusedB, eww1b, ew_b1, nullptr, nullptr, BIG, hidden, NN, 256, DD);
    // 7: ew
    ew_kernel<<<dim3(NN / 4), blk, 0, stream>>>(hidden, ew_w2, ew_b2, ew_out);
    // 8: S = fused @ fused^T (bf16), symmetric
    gemm_sym<<<dim3(64, 64), blk, 0, stream>>>(fusedB, Sb);
    // 9: top-16 + softmax stats
    topk_bf16<<<dim3(NN / 4), blk, 0, stream>>>(Sb, topv, topi);
    // 10: H := 0 (fast fill path)
    hipMemsetAsync(Hf, 0, (size_t)NN * NN * sizeof(float), stream);
    // 11: fused scatter + conditional diag
    scatter_diag<<<dim3((NN * 16 + NN) / 256), blk, 0, stream>>>(topv, topi, Hf);
}